// Round 6
// baseline (1468.980 us; speedup 1.0000x reference)
//
#include <hip/hip_runtime.h>
#include <hip/hip_bf16.h>

#define NT   4096
#define NH   12
#define INS  256
#define DOUT 128
#define D1   129

typedef short bf16x8  __attribute__((ext_vector_type(8)));
typedef float f32x4   __attribute__((ext_vector_type(4)));
typedef float f32x16  __attribute__((ext_vector_type(16)));

__device__ __forceinline__ short f2bf(float f) {
  union { __hip_bfloat16 h; short s; } u;
  u.h = __float2bfloat16(f);
  return u.s;
}

#define MFMA16(a,b,c) __builtin_amdgcn_mfma_f32_16x16x32_bf16((a),(b),(c),0,0,0)
#define MFMA32(a,b,c) __builtin_amdgcn_mfma_f32_32x32x16_bf16((a),(b),(c),0,0,0)

#define GL2LDS(gp, lp) \
  __builtin_amdgcn_global_load_lds((const __attribute__((address_space(1))) unsigned*)(gp), \
                                   (__attribute__((address_space(3))) unsigned*)(lp), 16, 0, 0)

// ---------------- conversion kernels ----------------

__global__ void k_cvt_xs(const float* __restrict__ xl, short* __restrict__ xs) {
  int i = blockIdx.x * 256 + threadIdx.x;       // 0 .. NT*INS-1
  int row = i >> 8, col = i & 255;
  xs[i] = f2bf(xl[row * 257 + 1 + col]);
}

__global__ void k_cvt_w(const float* __restrict__ w0, const float* __restrict__ w1,
                        const float* __restrict__ w2, short* __restrict__ dst) {
  int i = blockIdx.x * 256 + threadIdx.x;       // 0 .. NH*DOUT*INS-1
  const float* s = blockIdx.y == 0 ? w0 : (blockIdx.y == 1 ? w1 : w2);
  dst[(size_t)blockIdx.y * (NH * DOUT * INS) + i] = f2bf(s[i]);
}

// ---------------- projection: s = xs@W^T + b ; t = sqrt(|s|^2+1) ----------------
// grid (NT/128, NH, 3), block 256 (4 waves, each 32 rows x 128 cols).
// Q (z==0) pre-scaled by c2 = 2*log2(e)/scale so attention does p = exp2(qs.ks - qt*kt).
// kt/vt are written in crow-PERMUTED order so k_attn lanes load them contiguously.

__launch_bounds__(256, 2)
__global__ void k_proj(const short* __restrict__ xs, const short* __restrict__ Wb,
                       const float* __restrict__ b0, const float* __restrict__ b1,
                       const float* __restrict__ b2, const float* __restrict__ scalep,
                       short* __restrict__ Qb, short* __restrict__ Kb, short* __restrict__ VT,
                       float* __restrict__ qt, float* __restrict__ ktP, float* __restrict__ vtP) {
  __shared__ __align__(16) short lds_t[128 * 144];
  int t = threadIdx.x, l = t & 63, w = t >> 6;
  int lr = l & 15, lg = l >> 4;
  int h = blockIdx.y, z = blockIdx.z;
  int n0w = blockIdx.x * 128 + w * 32;
  const short* Wh = Wb + ((size_t)z * NH + h) * DOUT * INS;
  const float* bias = z == 0 ? b0 : (z == 1 ? b1 : b2);

  f32x4 acc[2][8] = {};
#pragma unroll
  for (int dk = 0; dk < 8; ++dk) {
    bf16x8 a[2], b[8];
#pragma unroll
    for (int qf = 0; qf < 2; ++qf)
      a[qf] = *(const bf16x8*)(xs + (size_t)(n0w + 16 * qf + lr) * INS + dk * 32 + lg * 8);
#pragma unroll
    for (int cf = 0; cf < 8; ++cf)
      b[cf] = *(const bf16x8*)(Wh + (size_t)(lr + 16 * cf) * INS + dk * 32 + lg * 8);
#pragma unroll
    for (int qf = 0; qf < 2; ++qf)
#pragma unroll
      for (int cf = 0; cf < 8; ++cf)
        acc[qf][cf] = MFMA16(a[qf], b[cf], acc[qf][cf]);
  }

  float tval[2][4];
#pragma unroll
  for (int qf = 0; qf < 2; ++qf) {
    float ssq[4] = {0.f, 0.f, 0.f, 0.f};
#pragma unroll
    for (int cf = 0; cf < 8; ++cf) {
      float bv = bias[h * DOUT + lr + 16 * cf];
#pragma unroll
      for (int r = 0; r < 4; ++r) {
        acc[qf][cf][r] += bv;
        ssq[r] += acc[qf][cf][r] * acc[qf][cf][r];
      }
    }
#pragma unroll
    for (int r = 0; r < 4; ++r) {
      float s = ssq[r];
      s += __shfl_xor(s, 1); s += __shfl_xor(s, 2);
      s += __shfl_xor(s, 4); s += __shfl_xor(s, 8);
      tval[qf][r] = sqrtf(s + 1.0f);
    }
  }

  float c2 = 2.0f * 1.442695040888963f / scalep[0];

  if (z < 2) {
    float f = (z == 0) ? c2 : 1.0f;
    // stage [n_local][d], stride 136 shorts
#pragma unroll
    for (int qf = 0; qf < 2; ++qf)
#pragma unroll
      for (int cf = 0; cf < 8; ++cf)
#pragma unroll
        for (int r = 0; r < 4; ++r)
          lds_t[(w * 32 + 16 * qf + lg * 4 + r) * 136 + lr + 16 * cf] = f2bf(acc[qf][cf][r] * f);
    if (lr == 0) {
#pragma unroll
      for (int qf = 0; qf < 2; ++qf)
#pragma unroll
        for (int r = 0; r < 4; ++r) {
          int n = n0w + 16 * qf + lg * 4 + r;
          if (z == 0) {
            qt[(size_t)h * NT + n] = tval[qf][r] * f;
          } else {
            int ml = n & 31, g = n >> 5;
            int hh = (ml >> 2) & 1, j = (ml & 3) + 4 * (ml >> 3);
            ktP[(size_t)h * NT + g * 32 + hh * 16 + j] = tval[qf][r];
          }
        }
    }
    __syncthreads();
    int row = t >> 1, half = t & 1;
    const short* src = lds_t + row * 136 + half * 64;
    short* dst = (z == 0 ? Qb : Kb) + ((size_t)h * NT + blockIdx.x * 128 + row) * DOUT + half * 64;
#pragma unroll
    for (int j = 0; j < 8; ++j)
      *(bf16x8*)(dst + j * 8) = *(const bf16x8*)(src + j * 8);
  } else {
    // V: stage transposed [d][n_local], stride 144
#pragma unroll
    for (int qf = 0; qf < 2; ++qf)
#pragma unroll
      for (int cf = 0; cf < 8; ++cf)
#pragma unroll
        for (int r = 0; r < 4; ++r)
          lds_t[(lr + 16 * cf) * 144 + w * 32 + 16 * qf + lg * 4 + r] = f2bf(acc[qf][cf][r]);
    if (lr == 0) {
#pragma unroll
      for (int qf = 0; qf < 2; ++qf)
#pragma unroll
        for (int r = 0; r < 4; ++r) {
          int n = n0w + 16 * qf + lg * 4 + r;
          int ml = n & 31, g = n >> 5;
          int hh = (ml >> 2) & 1, j = (ml & 3) + 4 * (ml >> 3);
          vtP[(size_t)h * NT + g * 32 + hh * 16 + j] = tval[qf][r];
        }
    }
    __syncthreads();
    int d = t >> 1, half = t & 1;
    const short* src = lds_t + d * 144 + half * 64;
    short* dst = VT + ((size_t)h * DOUT + d) * NT + blockIdx.x * 128 + half * 64;
#pragma unroll
    for (int j = 0; j < 8; ++j)
      *(bf16x8*)(dst + j * 8) = *(const bf16x8*)(src + j * 8);
  }
}

// ---------------- flash attention: swapped-operand 32x32x16, P in-register ----------------
// S^T = mfma(A=K, B=Q); max-free softmax (Lorentz logits <= 0); scale-invariant norms.
// P^T fragments via cvt_pk_bf16 + permlane32_swap; O^T = mfma(A=V^T, B=P^T).
// KV split nz ways (nz = gridDim.z). Partials are linear ->
//   ATOMIC=0: each (z,h,q-range) has a UNIQUE writer -> plain coalesced stores into
//             per-z buffers partz[z] (stride 128) + avtz[z]. No memset needed.
//   ATOMIC=1: all z atomicAdd into buffer 0 (small-workspace fallback; memset'd).
// grid (NT/128, NH, nz), block 256 (4 waves x 32 q). LDS 32KB -> 5 blocks/CU.

template <int ATOMIC>
__launch_bounds__(256, 5)
__global__ void k_attn(const short* __restrict__ Qb, const short* __restrict__ Kb,
                       const short* __restrict__ VT,
                       const float* __restrict__ qt, const float* __restrict__ ktP,
                       const float* __restrict__ vtP,
                       float* __restrict__ partz, float* __restrict__ avtz) {
  __shared__ __align__(16) char lds_all[32768];
  char* lds_k = lds_all;            // 16KB: [m][slot16] swizzled: slot ^= (m&15)
  char* lds_v = lds_all + 16384;    // 16KB: [d][slot16] swizzled: slot ^= (d&7)

  int t = threadIdx.x, l = t & 63, w = t >> 6;
  int ql = l & 31, hi = l >> 5;
  int h = blockIdx.y, z = blockIdx.z;
  int nz = gridDim.z;
  int kperz = NT / (nz * 64);       // key tiles per z
  int n0w = blockIdx.x * 128 + w * 32;
  int n = n0w + ql;

  const short* Qh = Qb + (size_t)h * NT * DOUT;
  const short* Kh = Kb + (size_t)h * NT * DOUT;
  const short* VTh = VT + (size_t)h * DOUT * NT;
  const float* ktPh = ktP + (size_t)h * NT;
  const float* vtPh = vtP + (size_t)h * NT;

  // Q as B-fragments: col=q=lane&31, k = dk*16 + hi*8 + e  (pre-scaled by c2)
  bf16x8 bq[8];
#pragma unroll
  for (int dk = 0; dk < 8; ++dk)
    bq[dk] = *(const bf16x8*)(Qh + (size_t)n * DOUT + dk * 16 + hi * 8);
  float qc2 = qt[(size_t)h * NT + n];

  f32x16 accO[4] = {};
  float avt = 0.f;

  int mz = z * (NT / nz);

  // prologue: issue K tile 0 (source pre-swizzled, LDS linear)
#pragma unroll
  for (int it = 0; it < 4; ++it) {
    int c = t + it * 256;
    int m = c >> 4, s = c & 15;
    GL2LDS(Kh + (size_t)(mz + m) * DOUT + ((s ^ (m & 15)) * 8), lds_k + c * 16);
  }

  for (int ktile = 0; ktile < kperz; ++ktile) {
    int m0 = mz + ktile * 64;
    __syncthreads();   // K_t resident; lds_v free (prev PV done)

    // issue V_t (consumed after mid-barrier; latency hidden under QK^T+softmax)
#pragma unroll
    for (int it = 0; it < 4; ++it) {
      int c = t + it * 256;
      int d = c >> 3, s = c & 7;
      GL2LDS(VTh + (size_t)d * NT + m0 + ((s ^ (d & 7)) * 8), lds_v + c * 16);
    }

    bf16x8 pfrag[4];
#pragma unroll
    for (int mf = 0; mf < 2; ++mf) {
      // ---- QK^T (spatial): S^T tile, rows m = mf*32 + ql ----
      f32x16 accS = {};
      int m = mf * 32 + ql;
      int rowb = m * 256;
      int sx = m & 15;
      __builtin_amdgcn_s_setprio(1);
#pragma unroll
      for (int dk = 0; dk < 8; ++dk) {
        bf16x8 ak = *(const bf16x8*)(lds_k + rowb + (((dk * 2 + hi) ^ sx) * 16));
        accS = MFMA32(ak, bq[dk], accS);
      }
      __builtin_amdgcn_s_setprio(0);

      // ---- softmax + pack (max-free): p[j] = exp2(accS[j] - qc2*ktP[j]) ----
      const float* ktm = ktPh + m0 + mf * 32 + hi * 16;
      const float* vtm = vtPh + m0 + mf * 32 + hi * 16;
      unsigned pk[8];
#pragma unroll
      for (int i4 = 0; i4 < 4; ++i4) {
        f32x4 kt4 = *(const f32x4*)(ktm + i4 * 4);
        f32x4 vt4 = *(const f32x4*)(vtm + i4 * 4);
#pragma unroll
        for (int ii = 0; ii < 2; ++ii) {
          float a0 = fmaf(-qc2, kt4[2 * ii],     accS[i4 * 4 + 2 * ii]);
          float a1 = fmaf(-qc2, kt4[2 * ii + 1], accS[i4 * 4 + 2 * ii + 1]);
          float p0, p1;
          asm("v_exp_f32 %0, %1" : "=v"(p0) : "v"(a0));
          asm("v_exp_f32 %0, %1" : "=v"(p1) : "v"(a1));
          avt = fmaf(p0, vt4[2 * ii], avt);
          avt = fmaf(p1, vt4[2 * ii + 1], avt);
          unsigned pw;
          asm("v_cvt_pk_bf16_f32 %0, %1, %2" : "=v"(pw) : "v"(p0), "v"(p1));
          pk[i4 * 2 + ii] = pw;
        }
      }
      // redistribute: frag(ks) word pattern via permlane32_swap (pairs pk_i <-> pk_{i+2})
      asm volatile("v_permlane32_swap_b32 %0, %1" : "+v"(pk[0]), "+v"(pk[2]));
      asm volatile("v_permlane32_swap_b32 %0, %1" : "+v"(pk[1]), "+v"(pk[3]));
      asm volatile("v_permlane32_swap_b32 %0, %1" : "+v"(pk[4]), "+v"(pk[6]));
      asm volatile("v_permlane32_swap_b32 %0, %1" : "+v"(pk[5]), "+v"(pk[7]));
      union { unsigned u[4]; bf16x8 v; } f0, f1;
      f0.u[0] = pk[0]; f0.u[1] = pk[1]; f0.u[2] = pk[2]; f0.u[3] = pk[3];
      f1.u[0] = pk[4]; f1.u[1] = pk[5]; f1.u[2] = pk[6]; f1.u[3] = pk[7];
      pfrag[2 * mf] = f0.v;
      pfrag[2 * mf + 1] = f1.v;
    }

    __syncthreads();   // V_t resident; lds_k consumed by all waves

    // issue K_{t+1} (latency hidden under PV)
    if (ktile + 1 < kperz) {
      int m1 = m0 + 64;
#pragma unroll
      for (int it = 0; it < 4; ++it) {
        int c = t + it * 256;
        int m = c >> 4, s = c & 15;
        GL2LDS(Kh + (size_t)(m1 + m) * DOUT + ((s ^ (m & 15)) * 8), lds_k + c * 16);
      }
    }

    // ---- PV: O^T += V^T(d x m) . P^T(m x q) ----
    __builtin_amdgcn_s_setprio(1);
#pragma unroll
    for (int ks = 0; ks < 4; ++ks) {
#pragma unroll
      for (int df = 0; df < 4; ++df) {
        int d = df * 32 + ql;
        bf16x8 av = *(const bf16x8*)(lds_v + d * 128 + (((ks * 2 + hi) ^ (d & 7)) * 16));
        accO[df] = MFMA32(av, pfrag[ks], accO[df]);
      }
    }
    __builtin_amdgcn_s_setprio(0);
  }

  // ---- epilogue: per-wave LDS transpose -> coalesced plain stores (or atomics) ----
  __syncthreads();   // all waves done with lds_k/lds_v
  float* sc = (float*)(lds_all + w * 8192);   // 32 q x 64 d floats, XOR-swizzled (dl^ql)
  int zb = ATOMIC ? 0 : z;
  float* wbase = partz + (((size_t)zb * NH + h) * NT + n0w) * 128;
#pragma unroll
  for (int dh = 0; dh < 2; ++dh) {
#pragma unroll
    for (int j = 0; j < 2; ++j)
#pragma unroll
      for (int r = 0; r < 16; ++r) {
        int dl = j * 32 + (r & 3) + 8 * (r >> 2) + 4 * hi;
        sc[ql * 64 + (dl ^ ql)] = accO[2 * dh + j][r];
      }
    __syncthreads();
#pragma unroll
    for (int nl = 0; nl < 32; ++nl) {
      float v = sc[nl * 64 + (l ^ nl)];
      if (ATOMIC) atomicAdd(wbase + (size_t)nl * 128 + dh * 64 + l, v);
      else        wbase[(size_t)nl * 128 + dh * 64 + l] = v;
    }
    __syncthreads();
  }
  float avt2 = avt + __shfl_xor(avt, 32);
  if (l < 32) {
    float* ap = avtz + ((size_t)zb * NH + h) * NT + n0w + ql;
    if (ATOMIC) atomicAdd(ap, avt2);
    else        *ap = avt2;
  }
}

// ---------------- combine: midpoint-norm #1 per head, head sum, midpoint-norm #2 ----------------
// Sums nbuf z-partials; midpoint_norm scale-invariance -> no softmax denom, no 1/NH.

__global__ void k_comb(const float* __restrict__ partz, const float* __restrict__ avtz,
                       float* __restrict__ out, int nbuf) {
  int l = threadIdx.x & 63, w = threadIdx.x >> 6;
  int n = blockIdx.x * 4 + w;
  float acc_lo = 0.f, acc_hi = 0.f, acc_t = 0.f;
#pragma unroll
  for (int h = 0; h < NH; ++h) {
    float x = 0.f, y = 0.f, at = 0.f;
    for (int zb = 0; zb < nbuf; ++zb) {
      const float* p = partz + (((size_t)zb * NH + h) * NT + n) * 128;
      x += p[l]; y += p[64 + l];
      at += avtz[((size_t)zb * NH + h) * NT + n];
    }
    float sp = x * x + y * y;
    sp += __shfl_xor(sp, 1);  sp += __shfl_xor(sp, 2);
    sp += __shfl_xor(sp, 4);  sp += __shfl_xor(sp, 8);
    sp += __shfl_xor(sp, 16); sp += __shfl_xor(sp, 32);
    float inner = sp - at * at;
    float rd = 1.0f / sqrtf(fmaxf(fabsf(inner), 1e-8f));
    acc_lo += x * rd; acc_hi += y * rd; acc_t += at * rd;
  }
  float sp = acc_lo * acc_lo + acc_hi * acc_hi;
  sp += __shfl_xor(sp, 1);  sp += __shfl_xor(sp, 2);
  sp += __shfl_xor(sp, 4);  sp += __shfl_xor(sp, 8);
  sp += __shfl_xor(sp, 16); sp += __shfl_xor(sp, 32);
  float inner = sp - acc_t * acc_t;
  float rd = 1.0f / sqrtf(fmaxf(fabsf(inner), 1e-8f));
  float* orow = out + (size_t)n * D1;
  orow[1 + l] = acc_lo * rd;
  orow[65 + l] = acc_hi * rd;
  if (l == 0) orow[0] = acc_t * rd;
}

// ---------------- launch ----------------

extern "C" void kernel_launch(void* const* d_in, const int* in_sizes, int n_in,
                              void* d_out, int out_size, void* d_ws, size_t ws_size,
                              hipStream_t stream) {
  (void)in_sizes; (void)n_in; (void)out_size;
  const float* xl    = (const float*)d_in[0];
  const float* Wq    = (const float*)d_in[1];
  const float* bq    = (const float*)d_in[2];
  const float* Wk    = (const float*)d_in[3];
  const float* bk    = (const float*)d_in[4];
  const float* Wv    = (const float*)d_in[5];
  const float* bv    = (const float*)d_in[6];
  const float* scale = (const float*)d_in[7];
  // d_in[8] = bias: softmax shift-invariance + midpoint_norm scale-invariance -> no-op.
  float* out = (float*)d_out;

  char* ws = (char*)d_ws;
  size_t off = 0;
  auto alloc = [&](size_t b) { char* p = ws + off; off = (off + b + 255) & ~(size_t)255; return p; };
  auto al = [](size_t b) { return (b + 255) & ~(size_t)255; };

  // persistent buffers (live proj -> attn)
  short* Qb    = (short*)alloc((size_t)NH * NT * DOUT * 2);
  short* Kb    = (short*)alloc((size_t)NH * NT * DOUT * 2);
  short* VT    = (short*)alloc((size_t)NH * DOUT * NT * 2);
  float* qt    = (float*)alloc((size_t)NH * NT * 4);
  float* ktP   = (float*)alloc((size_t)NH * NT * 4);
  float* vtP   = (float*)alloc((size_t)NH * NT * 4);
  size_t base = off;

  // shared region: proj temporaries (xs, Wb) then reused for attention partials
  size_t xs_b = al((size_t)NT * INS * 2);
  size_t wb_b = al((size_t)3 * NH * DOUT * INS * 2);
  size_t projtmp = xs_b + wb_b;
  auto part_b = [&](int nb) {
    return al((size_t)nb * NH * NT * 128 * 4) + al((size_t)nb * NH * NT * 4);
  };

  // mode ladder on workspace size
  int nz, nbuf, atomic;
  if (ws_size >= base + (projtmp > part_b(4) ? projtmp : part_b(4))) {
    nz = 4; nbuf = 4; atomic = 0;
  } else if (ws_size >= base + (projtmp > part_b(2) ? projtmp : part_b(2))) {
    nz = 2; nbuf = 2; atomic = 0;
  } else {
    nz = 2; nbuf = 1; atomic = 1;
  }

  char* region = ws + base;
  short* xs    = (short*)region;
  short* Wb    = (short*)(region + xs_b);
  float* partz = (float*)region;                                    // aliases xs/Wb (dead by then)
  float* avtz  = (float*)(region + al((size_t)nbuf * NH * NT * 128 * 4));

  if (atomic)
    hipMemsetAsync(partz, 0, part_b(1), stream);

  k_cvt_xs<<<NT, 256, 0, stream>>>(xl, xs);
  k_cvt_w<<<dim3(NH * DOUT * INS / 256, 3), 256, 0, stream>>>(Wq, Wk, Wv, Wb);
  k_proj<<<dim3(NT / 128, NH, 3), 256, 0, stream>>>(xs, Wb, bq, bk, bv, scale, Qb, Kb, VT, qt, ktP, vtP);
  if (atomic)
    k_attn<1><<<dim3(NT / 128, NH, nz), 256, 0, stream>>>(Qb, Kb, VT, qt, ktP, vtP, partz, avtz);
  else
    k_attn<0><<<dim3(NT / 128, NH, nz), 256, 0, stream>>>(Qb, Kb, VT, qt, ktP, vtP, partz, avtz);
  k_comb<<<NT / 4, 256, 0, stream>>>(partz, avtz, out, nbuf);
}

// Round 7
// 584.161 us; speedup vs baseline: 2.5147x; 2.5147x over previous
//
#include <hip/hip_runtime.h>
#include <hip/hip_bf16.h>

#define NT   4096
#define NH   12
#define INS  256
#define DOUT 128
#define D1   129

typedef short bf16x8  __attribute__((ext_vector_type(8)));
typedef float f32x4   __attribute__((ext_vector_type(4)));
typedef float f32x16  __attribute__((ext_vector_type(16)));

__device__ __forceinline__ short f2bf(float f) {
  union { __hip_bfloat16 h; short s; } u;
  u.h = __float2bfloat16(f);
  return u.s;
}

#define MFMA16(a,b,c) __builtin_amdgcn_mfma_f32_16x16x32_bf16((a),(b),(c),0,0,0)
#define MFMA32(a,b,c) __builtin_amdgcn_mfma_f32_32x32x16_bf16((a),(b),(c),0,0,0)

#define GL2LDS(gp, lp) \
  __builtin_amdgcn_global_load_lds((const __attribute__((address_space(1))) unsigned*)(gp), \
                                   (__attribute__((address_space(3))) unsigned*)(lp), 16, 0, 0)

// ---------------- conversion kernels ----------------

__global__ void k_cvt_xs(const float* __restrict__ xl, short* __restrict__ xs) {
  int i = blockIdx.x * 256 + threadIdx.x;       // 0 .. NT*INS-1
  int row = i >> 8, col = i & 255;
  xs[i] = f2bf(xl[row * 257 + 1 + col]);
}

__global__ void k_cvt_w(const float* __restrict__ w0, const float* __restrict__ w1,
                        const float* __restrict__ w2, short* __restrict__ dst) {
  int i = blockIdx.x * 256 + threadIdx.x;       // 0 .. NH*DOUT*INS-1
  const float* s = blockIdx.y == 0 ? w0 : (blockIdx.y == 1 ? w1 : w2);
  dst[(size_t)blockIdx.y * (NH * DOUT * INS) + i] = f2bf(s[i]);
}

// ---------------- projection: s = xs@W^T + b ; t = sqrt(|s|^2+1) ----------------
// grid (NT/128, NH, 3), block 256 (4 waves, each 32 rows x 128 cols).
// Q (z==0) pre-scaled by c2 = 2*log2(e)/scale so attention does p = exp2(qs.ks - qt*kt).
// kt/vt are written in crow-PERMUTED order so k_attn lanes load them contiguously.

__launch_bounds__(256, 2)
__global__ void k_proj(const short* __restrict__ xs, const short* __restrict__ Wb,
                       const float* __restrict__ b0, const float* __restrict__ b1,
                       const float* __restrict__ b2, const float* __restrict__ scalep,
                       short* __restrict__ Qb, short* __restrict__ Kb, short* __restrict__ VT,
                       float* __restrict__ qt, float* __restrict__ ktP, float* __restrict__ vtP) {
  __shared__ __align__(16) short lds_t[128 * 144];
  int t = threadIdx.x, l = t & 63, w = t >> 6;
  int lr = l & 15, lg = l >> 4;
  int h = blockIdx.y, z = blockIdx.z;
  int n0w = blockIdx.x * 128 + w * 32;
  const short* Wh = Wb + ((size_t)z * NH + h) * DOUT * INS;
  const float* bias = z == 0 ? b0 : (z == 1 ? b1 : b2);

  f32x4 acc[2][8] = {};
#pragma unroll
  for (int dk = 0; dk < 8; ++dk) {
    bf16x8 a[2], b[8];
#pragma unroll
    for (int qf = 0; qf < 2; ++qf)
      a[qf] = *(const bf16x8*)(xs + (size_t)(n0w + 16 * qf + lr) * INS + dk * 32 + lg * 8);
#pragma unroll
    for (int cf = 0; cf < 8; ++cf)
      b[cf] = *(const bf16x8*)(Wh + (size_t)(lr + 16 * cf) * INS + dk * 32 + lg * 8);
#pragma unroll
    for (int qf = 0; qf < 2; ++qf)
#pragma unroll
      for (int cf = 0; cf < 8; ++cf)
        acc[qf][cf] = MFMA16(a[qf], b[cf], acc[qf][cf]);
  }

  float tval[2][4];
#pragma unroll
  for (int qf = 0; qf < 2; ++qf) {
    float ssq[4] = {0.f, 0.f, 0.f, 0.f};
#pragma unroll
    for (int cf = 0; cf < 8; ++cf) {
      float bv = bias[h * DOUT + lr + 16 * cf];
#pragma unroll
      for (int r = 0; r < 4; ++r) {
        acc[qf][cf][r] += bv;
        ssq[r] += acc[qf][cf][r] * acc[qf][cf][r];
      }
    }
#pragma unroll
    for (int r = 0; r < 4; ++r) {
      float s = ssq[r];
      s += __shfl_xor(s, 1); s += __shfl_xor(s, 2);
      s += __shfl_xor(s, 4); s += __shfl_xor(s, 8);
      tval[qf][r] = sqrtf(s + 1.0f);
    }
  }

  float c2 = 2.0f * 1.442695040888963f / scalep[0];

  if (z < 2) {
    float f = (z == 0) ? c2 : 1.0f;
    // stage [n_local][d], stride 136 shorts
#pragma unroll
    for (int qf = 0; qf < 2; ++qf)
#pragma unroll
      for (int cf = 0; cf < 8; ++cf)
#pragma unroll
        for (int r = 0; r < 4; ++r)
          lds_t[(w * 32 + 16 * qf + lg * 4 + r) * 136 + lr + 16 * cf] = f2bf(acc[qf][cf][r] * f);
    if (lr == 0) {
#pragma unroll
      for (int qf = 0; qf < 2; ++qf)
#pragma unroll
        for (int r = 0; r < 4; ++r) {
          int n = n0w + 16 * qf + lg * 4 + r;
          if (z == 0) {
            qt[(size_t)h * NT + n] = tval[qf][r] * f;
          } else {
            int ml = n & 31, g = n >> 5;
            int hh = (ml >> 2) & 1, j = (ml & 3) + 4 * (ml >> 3);
            ktP[(size_t)h * NT + g * 32 + hh * 16 + j] = tval[qf][r];
          }
        }
    }
    __syncthreads();
    int row = t >> 1, half = t & 1;
    const short* src = lds_t + row * 136 + half * 64;
    short* dst = (z == 0 ? Qb : Kb) + ((size_t)h * NT + blockIdx.x * 128 + row) * DOUT + half * 64;
#pragma unroll
    for (int j = 0; j < 8; ++j)
      *(bf16x8*)(dst + j * 8) = *(const bf16x8*)(src + j * 8);
  } else {
    // V: stage transposed [d][n_local], stride 144
#pragma unroll
    for (int qf = 0; qf < 2; ++qf)
#pragma unroll
      for (int cf = 0; cf < 8; ++cf)
#pragma unroll
        for (int r = 0; r < 4; ++r)
          lds_t[(lr + 16 * cf) * 144 + w * 32 + 16 * qf + lg * 4 + r] = f2bf(acc[qf][cf][r]);
    if (lr == 0) {
#pragma unroll
      for (int qf = 0; qf < 2; ++qf)
#pragma unroll
        for (int r = 0; r < 4; ++r) {
          int n = n0w + 16 * qf + lg * 4 + r;
          int ml = n & 31, g = n >> 5;
          int hh = (ml >> 2) & 1, j = (ml & 3) + 4 * (ml >> 3);
          vtP[(size_t)h * NT + g * 32 + hh * 16 + j] = tval[qf][r];
        }
    }
    __syncthreads();
    int d = t >> 1, half = t & 1;
    const short* src = lds_t + d * 144 + half * 64;
    short* dst = VT + ((size_t)h * DOUT + d) * NT + blockIdx.x * 128 + half * 64;
#pragma unroll
    for (int j = 0; j < 8; ++j)
      *(bf16x8*)(dst + j * 8) = *(const bf16x8*)(src + j * 8);
  }
}

// ---------------- flash attention: swapped-operand 32x32x16, P in-register ----------------
// S^T = mfma(A=K, B=Q); max-free softmax (Lorentz logits <= 0); scale-invariant norms.
// P^T fragments via cvt_pk_bf16 + permlane32_swap; O^T = mfma(A=V^T, B=P^T).
// KV split nz ways (nz = gridDim.z). Partials are linear ->
//   ATOMIC=0: each (z,h,q-range) has a UNIQUE writer -> plain coalesced stores into
//             per-z buffers partz[z] (stride 128) + avtz[z]. No memset needed.
//   ATOMIC=1: all z atomicAdd into buffer 0 (small-workspace fallback; memset'd).
// grid (NT/128, NH, nz), block 256 (4 waves x 32 q). LDS 32KB.
// __launch_bounds__(256,3): per-thread live state is ~150 unified regs (accO 64 f32 +
// bq 32 + pk/pfrag) -> 3 waves/EU max. Round-6's (256,5) forced a 102-reg budget ->
// accumulator SPILL -> 4.8 GB scratch traffic, 6.5x slower. DO NOT raise this bound.

template <int ATOMIC>
__launch_bounds__(256, 3)
__global__ void k_attn(const short* __restrict__ Qb, const short* __restrict__ Kb,
                       const short* __restrict__ VT,
                       const float* __restrict__ qt, const float* __restrict__ ktP,
                       const float* __restrict__ vtP,
                       float* __restrict__ partz, float* __restrict__ avtz) {
  __shared__ __align__(16) char lds_all[32768];
  char* lds_k = lds_all;            // 16KB: [m][slot16] swizzled: slot ^= (m&15)
  char* lds_v = lds_all + 16384;    // 16KB: [d][slot16] swizzled: slot ^= (d&7)

  int t = threadIdx.x, l = t & 63, w = t >> 6;
  int ql = l & 31, hi = l >> 5;
  int h = blockIdx.y, z = blockIdx.z;
  int nz = gridDim.z;
  int kperz = NT / (nz * 64);       // key tiles per z
  int n0w = blockIdx.x * 128 + w * 32;
  int n = n0w + ql;

  const short* Qh = Qb + (size_t)h * NT * DOUT;
  const short* Kh = Kb + (size_t)h * NT * DOUT;
  const short* VTh = VT + (size_t)h * DOUT * NT;
  const float* ktPh = ktP + (size_t)h * NT;
  const float* vtPh = vtP + (size_t)h * NT;

  // Q as B-fragments: col=q=lane&31, k = dk*16 + hi*8 + e  (pre-scaled by c2)
  bf16x8 bq[8];
#pragma unroll
  for (int dk = 0; dk < 8; ++dk)
    bq[dk] = *(const bf16x8*)(Qh + (size_t)n * DOUT + dk * 16 + hi * 8);
  float qc2 = qt[(size_t)h * NT + n];

  f32x16 accO[4] = {};
  float avt = 0.f;

  int mz = z * (NT / nz);

  // prologue: issue K tile 0 (source pre-swizzled, LDS linear)
#pragma unroll
  for (int it = 0; it < 4; ++it) {
    int c = t + it * 256;
    int m = c >> 4, s = c & 15;
    GL2LDS(Kh + (size_t)(mz + m) * DOUT + ((s ^ (m & 15)) * 8), lds_k + c * 16);
  }

  for (int ktile = 0; ktile < kperz; ++ktile) {
    int m0 = mz + ktile * 64;
    __syncthreads();   // K_t resident; lds_v free (prev PV done)

    // issue V_t (consumed after mid-barrier; latency hidden under QK^T+softmax)
#pragma unroll
    for (int it = 0; it < 4; ++it) {
      int c = t + it * 256;
      int d = c >> 3, s = c & 7;
      GL2LDS(VTh + (size_t)d * NT + m0 + ((s ^ (d & 7)) * 8), lds_v + c * 16);
    }

    bf16x8 pfrag[4];
#pragma unroll
    for (int mf = 0; mf < 2; ++mf) {
      // ---- QK^T (spatial): S^T tile, rows m = mf*32 + ql ----
      f32x16 accS = {};
      int m = mf * 32 + ql;
      int rowb = m * 256;
      int sx = m & 15;
      __builtin_amdgcn_s_setprio(1);
#pragma unroll
      for (int dk = 0; dk < 8; ++dk) {
        bf16x8 ak = *(const bf16x8*)(lds_k + rowb + (((dk * 2 + hi) ^ sx) * 16));
        accS = MFMA32(ak, bq[dk], accS);
      }
      __builtin_amdgcn_s_setprio(0);

      // ---- softmax + pack (max-free): p[j] = exp2(accS[j] - qc2*ktP[j]) ----
      const float* ktm = ktPh + m0 + mf * 32 + hi * 16;
      const float* vtm = vtPh + m0 + mf * 32 + hi * 16;
      unsigned pk[8];
#pragma unroll
      for (int i4 = 0; i4 < 4; ++i4) {
        f32x4 kt4 = *(const f32x4*)(ktm + i4 * 4);
        f32x4 vt4 = *(const f32x4*)(vtm + i4 * 4);
#pragma unroll
        for (int ii = 0; ii < 2; ++ii) {
          float a0 = fmaf(-qc2, kt4[2 * ii],     accS[i4 * 4 + 2 * ii]);
          float a1 = fmaf(-qc2, kt4[2 * ii + 1], accS[i4 * 4 + 2 * ii + 1]);
          float p0, p1;
          asm("v_exp_f32 %0, %1" : "=v"(p0) : "v"(a0));
          asm("v_exp_f32 %0, %1" : "=v"(p1) : "v"(a1));
          avt = fmaf(p0, vt4[2 * ii], avt);
          avt = fmaf(p1, vt4[2 * ii + 1], avt);
          unsigned pw;
          asm("v_cvt_pk_bf16_f32 %0, %1, %2" : "=v"(pw) : "v"(p0), "v"(p1));
          pk[i4 * 2 + ii] = pw;
        }
      }
      // redistribute: frag(ks) word pattern via permlane32_swap (pairs pk_i <-> pk_{i+2})
      asm volatile("v_permlane32_swap_b32 %0, %1" : "+v"(pk[0]), "+v"(pk[2]));
      asm volatile("v_permlane32_swap_b32 %0, %1" : "+v"(pk[1]), "+v"(pk[3]));
      asm volatile("v_permlane32_swap_b32 %0, %1" : "+v"(pk[4]), "+v"(pk[6]));
      asm volatile("v_permlane32_swap_b32 %0, %1" : "+v"(pk[5]), "+v"(pk[7]));
      union { unsigned u[4]; bf16x8 v; } f0, f1;
      f0.u[0] = pk[0]; f0.u[1] = pk[1]; f0.u[2] = pk[2]; f0.u[3] = pk[3];
      f1.u[0] = pk[4]; f1.u[1] = pk[5]; f1.u[2] = pk[6]; f1.u[3] = pk[7];
      pfrag[2 * mf] = f0.v;
      pfrag[2 * mf + 1] = f1.v;
    }

    __syncthreads();   // V_t resident; lds_k consumed by all waves

    // issue K_{t+1} (latency hidden under PV)
    if (ktile + 1 < kperz) {
      int m1 = m0 + 64;
#pragma unroll
      for (int it = 0; it < 4; ++it) {
        int c = t + it * 256;
        int m = c >> 4, s = c & 15;
        GL2LDS(Kh + (size_t)(m1 + m) * DOUT + ((s ^ (m & 15)) * 8), lds_k + c * 16);
      }
    }

    // ---- PV: O^T += V^T(d x m) . P^T(m x q) ----
    __builtin_amdgcn_s_setprio(1);
#pragma unroll
    for (int ks = 0; ks < 4; ++ks) {
#pragma unroll
      for (int df = 0; df < 4; ++df) {
        int d = df * 32 + ql;
        bf16x8 av = *(const bf16x8*)(lds_v + d * 128 + (((ks * 2 + hi) ^ (d & 7)) * 16));
        accO[df] = MFMA32(av, pfrag[ks], accO[df]);
      }
    }
    __builtin_amdgcn_s_setprio(0);
  }

  // ---- epilogue: per-wave LDS transpose -> coalesced plain stores (or atomics) ----
  __syncthreads();   // all waves done with lds_k/lds_v
  float* sc = (float*)(lds_all + w * 8192);   // 32 q x 64 d floats, XOR-swizzled (dl^ql)
  int zb = ATOMIC ? 0 : z;
  float* wbase = partz + (((size_t)zb * NH + h) * NT + n0w) * 128;
#pragma unroll
  for (int dh = 0; dh < 2; ++dh) {
#pragma unroll
    for (int j = 0; j < 2; ++j)
#pragma unroll
      for (int r = 0; r < 16; ++r) {
        int dl = j * 32 + (r & 3) + 8 * (r >> 2) + 4 * hi;
        sc[ql * 64 + (dl ^ ql)] = accO[2 * dh + j][r];
      }
    __syncthreads();
#pragma unroll
    for (int nl = 0; nl < 32; ++nl) {
      float v = sc[nl * 64 + (l ^ nl)];
      if (ATOMIC) atomicAdd(wbase + (size_t)nl * 128 + dh * 64 + l, v);
      else        wbase[(size_t)nl * 128 + dh * 64 + l] = v;
    }
    __syncthreads();
  }
  float avt2 = avt + __shfl_xor(avt, 32);
  if (l < 32) {
    float* ap = avtz + ((size_t)zb * NH + h) * NT + n0w + ql;
    if (ATOMIC) atomicAdd(ap, avt2);
    else        *ap = avt2;
  }
}

// ---------------- combine: midpoint-norm #1 per head, head sum, midpoint-norm #2 ----------------
// Sums nbuf z-partials; midpoint_norm scale-invariance -> no softmax denom, no 1/NH.

__global__ void k_comb(const float* __restrict__ partz, const float* __restrict__ avtz,
                       float* __restrict__ out, int nbuf) {
  int l = threadIdx.x & 63, w = threadIdx.x >> 6;
  int n = blockIdx.x * 4 + w;
  float acc_lo = 0.f, acc_hi = 0.f, acc_t = 0.f;
#pragma unroll
  for (int h = 0; h < NH; ++h) {
    float x = 0.f, y = 0.f, at = 0.f;
    for (int zb = 0; zb < nbuf; ++zb) {
      const float* p = partz + (((size_t)zb * NH + h) * NT + n) * 128;
      x += p[l]; y += p[64 + l];
      at += avtz[((size_t)zb * NH + h) * NT + n];
    }
    float sp = x * x + y * y;
    sp += __shfl_xor(sp, 1);  sp += __shfl_xor(sp, 2);
    sp += __shfl_xor(sp, 4);  sp += __shfl_xor(sp, 8);
    sp += __shfl_xor(sp, 16); sp += __shfl_xor(sp, 32);
    float inner = sp - at * at;
    float rd = 1.0f / sqrtf(fmaxf(fabsf(inner), 1e-8f));
    acc_lo += x * rd; acc_hi += y * rd; acc_t += at * rd;
  }
  float sp = acc_lo * acc_lo + acc_hi * acc_hi;
  sp += __shfl_xor(sp, 1);  sp += __shfl_xor(sp, 2);
  sp += __shfl_xor(sp, 4);  sp += __shfl_xor(sp, 8);
  sp += __shfl_xor(sp, 16); sp += __shfl_xor(sp, 32);
  float inner = sp - acc_t * acc_t;
  float rd = 1.0f / sqrtf(fmaxf(fabsf(inner), 1e-8f));
  float* orow = out + (size_t)n * D1;
  orow[1 + l] = acc_lo * rd;
  orow[65 + l] = acc_hi * rd;
  if (l == 0) orow[0] = acc_t * rd;
}

// ---------------- launch ----------------

extern "C" void kernel_launch(void* const* d_in, const int* in_sizes, int n_in,
                              void* d_out, int out_size, void* d_ws, size_t ws_size,
                              hipStream_t stream) {
  (void)in_sizes; (void)n_in; (void)out_size;
  const float* xl    = (const float*)d_in[0];
  const float* Wq    = (const float*)d_in[1];
  const float* bq    = (const float*)d_in[2];
  const float* Wk    = (const float*)d_in[3];
  const float* bk    = (const float*)d_in[4];
  const float* Wv    = (const float*)d_in[5];
  const float* bv    = (const float*)d_in[6];
  const float* scale = (const float*)d_in[7];
  // d_in[8] = bias: softmax shift-invariance + midpoint_norm scale-invariance -> no-op.
  float* out = (float*)d_out;

  char* ws = (char*)d_ws;
  size_t off = 0;
  auto alloc = [&](size_t b) { char* p = ws + off; off = (off + b + 255) & ~(size_t)255; return p; };
  auto al = [](size_t b) { return (b + 255) & ~(size_t)255; };

  // persistent buffers (live proj -> attn)
  short* Qb    = (short*)alloc((size_t)NH * NT * DOUT * 2);
  short* Kb    = (short*)alloc((size_t)NH * NT * DOUT * 2);
  short* VT    = (short*)alloc((size_t)NH * DOUT * NT * 2);
  float* qt    = (float*)alloc((size_t)NH * NT * 4);
  float* ktP   = (float*)alloc((size_t)NH * NT * 4);
  float* vtP   = (float*)alloc((size_t)NH * NT * 4);
  size_t base = off;

  // shared region: proj temporaries (xs, Wb) then reused for attention partials
  size_t xs_b = al((size_t)NT * INS * 2);
  size_t wb_b = al((size_t)3 * NH * DOUT * INS * 2);
  size_t projtmp = xs_b + wb_b;
  auto part_b = [&](int nb) {
    return al((size_t)nb * NH * NT * 128 * 4) + al((size_t)nb * NH * NT * 4);
  };

  // mode ladder on workspace size
  int nz, nbuf, atomic;
  if (ws_size >= base + (projtmp > part_b(4) ? projtmp : part_b(4))) {
    nz = 4; nbuf = 4; atomic = 0;
  } else if (ws_size >= base + (projtmp > part_b(2) ? projtmp : part_b(2))) {
    nz = 2; nbuf = 2; atomic = 0;
  } else {
    nz = 2; nbuf = 1; atomic = 1;
  }

  char* region = ws + base;
  short* xs    = (short*)region;
  short* Wb    = (short*)(region + xs_b);
  float* partz = (float*)region;                                    // aliases xs/Wb (dead by then)
  float* avtz  = (float*)(region + al((size_t)nbuf * NH * NT * 128 * 4));

  if (atomic)
    hipMemsetAsync(partz, 0, part_b(1), stream);

  k_cvt_xs<<<NT, 256, 0, stream>>>(xl, xs);
  k_cvt_w<<<dim3(NH * DOUT * INS / 256, 3), 256, 0, stream>>>(Wq, Wk, Wv, Wb);
  k_proj<<<dim3(NT / 128, NH, 3), 256, 0, stream>>>(xs, Wb, bq, bk, bv, scale, Qb, Kb, VT, qt, ktP, vtP);
  if (atomic)
    k_attn<1><<<dim3(NT / 128, NH, nz), 256, 0, stream>>>(Qb, Kb, VT, qt, ktP, vtP, partz, avtz);
  else
    k_attn<0><<<dim3(NT / 128, NH, nz), 256, 0, stream>>>(Qb, Kb, VT, qt, ktP, vtP, partz, avtz);
  k_comb<<<NT / 4, 256, 0, stream>>>(partz, avtz, out, nbuf);
}

// Round 8
// 293.025 us; speedup vs baseline: 5.0132x; 1.9936x over previous
//
#include <hip/hip_runtime.h>
#include <hip/hip_bf16.h>

#define NT   4096
#define NH   12
#define INS  256
#define DOUT 128
#define D1   129

typedef short bf16x8  __attribute__((ext_vector_type(8)));
typedef float f32x4   __attribute__((ext_vector_type(4)));
typedef float f32x16  __attribute__((ext_vector_type(16)));

__device__ __forceinline__ short f2bf(float f) {
  union { __hip_bfloat16 h; short s; } u;
  u.h = __float2bfloat16(f);
  return u.s;
}

#define MFMA16(a,b,c) __builtin_amdgcn_mfma_f32_16x16x32_bf16((a),(b),(c),0,0,0)
#define MFMA32(a,b,c) __builtin_amdgcn_mfma_f32_32x32x16_bf16((a),(b),(c),0,0,0)

#define GL2LDS(gp, lp) \
  __builtin_amdgcn_global_load_lds((const __attribute__((address_space(1))) unsigned*)(gp), \
                                   (__attribute__((address_space(3))) unsigned*)(lp), 16, 0, 0)

// ---------------- conversion kernels ----------------

__global__ void k_cvt_xs(const float* __restrict__ xl, short* __restrict__ xs) {
  int i = blockIdx.x * 256 + threadIdx.x;       // 0 .. NT*INS-1
  int row = i >> 8, col = i & 255;
  xs[i] = f2bf(xl[row * 257 + 1 + col]);
}

__global__ void k_cvt_w(const float* __restrict__ w0, const float* __restrict__ w1,
                        const float* __restrict__ w2, short* __restrict__ dst) {
  int i = blockIdx.x * 256 + threadIdx.x;       // 0 .. NH*DOUT*INS-1
  const float* s = blockIdx.y == 0 ? w0 : (blockIdx.y == 1 ? w1 : w2);
  dst[(size_t)blockIdx.y * (NH * DOUT * INS) + i] = f2bf(s[i]);
}

// ---------------- projection: s = xs@W^T + b ; t = sqrt(|s|^2+1) ----------------
// grid (NT/128, NH, 3), block 256 (4 waves, each 32 rows x 128 cols).
// Q (z==0) pre-scaled by c2 = 2*log2(e)/scale so attention does p = exp2(qs.ks - qt*kt).
// kt/vt are written in crow-PERMUTED order so k_attn lanes load them contiguously.

__launch_bounds__(256, 2)
__global__ void k_proj(const short* __restrict__ xs, const short* __restrict__ Wb,
                       const float* __restrict__ b0, const float* __restrict__ b1,
                       const float* __restrict__ b2, const float* __restrict__ scalep,
                       short* __restrict__ Qb, short* __restrict__ Kb, short* __restrict__ VT,
                       float* __restrict__ qt, float* __restrict__ ktP, float* __restrict__ vtP) {
  __shared__ __align__(16) short lds_t[128 * 144];
  int t = threadIdx.x, l = t & 63, w = t >> 6;
  int lr = l & 15, lg = l >> 4;
  int h = blockIdx.y, z = blockIdx.z;
  int n0w = blockIdx.x * 128 + w * 32;
  const short* Wh = Wb + ((size_t)z * NH + h) * DOUT * INS;
  const float* bias = z == 0 ? b0 : (z == 1 ? b1 : b2);

  f32x4 acc[2][8] = {};
#pragma unroll
  for (int dk = 0; dk < 8; ++dk) {
    bf16x8 a[2], b[8];
#pragma unroll
    for (int qf = 0; qf < 2; ++qf)
      a[qf] = *(const bf16x8*)(xs + (size_t)(n0w + 16 * qf + lr) * INS + dk * 32 + lg * 8);
#pragma unroll
    for (int cf = 0; cf < 8; ++cf)
      b[cf] = *(const bf16x8*)(Wh + (size_t)(lr + 16 * cf) * INS + dk * 32 + lg * 8);
#pragma unroll
    for (int qf = 0; qf < 2; ++qf)
#pragma unroll
      for (int cf = 0; cf < 8; ++cf)
        acc[qf][cf] = MFMA16(a[qf], b[cf], acc[qf][cf]);
  }

  float tval[2][4];
#pragma unroll
  for (int qf = 0; qf < 2; ++qf) {
    float ssq[4] = {0.f, 0.f, 0.f, 0.f};
#pragma unroll
    for (int cf = 0; cf < 8; ++cf) {
      float bv = bias[h * DOUT + lr + 16 * cf];
#pragma unroll
      for (int r = 0; r < 4; ++r) {
        acc[qf][cf][r] += bv;
        ssq[r] += acc[qf][cf][r] * acc[qf][cf][r];
      }
    }
#pragma unroll
    for (int r = 0; r < 4; ++r) {
      float s = ssq[r];
      s += __shfl_xor(s, 1); s += __shfl_xor(s, 2);
      s += __shfl_xor(s, 4); s += __shfl_xor(s, 8);
      tval[qf][r] = sqrtf(s + 1.0f);
    }
  }

  float c2 = 2.0f * 1.442695040888963f / scalep[0];

  if (z < 2) {
    float f = (z == 0) ? c2 : 1.0f;
    // stage [n_local][d], stride 136 shorts
#pragma unroll
    for (int qf = 0; qf < 2; ++qf)
#pragma unroll
      for (int cf = 0; cf < 8; ++cf)
#pragma unroll
        for (int r = 0; r < 4; ++r)
          lds_t[(w * 32 + 16 * qf + lg * 4 + r) * 136 + lr + 16 * cf] = f2bf(acc[qf][cf][r] * f);
    if (lr == 0) {
#pragma unroll
      for (int qf = 0; qf < 2; ++qf)
#pragma unroll
        for (int r = 0; r < 4; ++r) {
          int n = n0w + 16 * qf + lg * 4 + r;
          if (z == 0) {
            qt[(size_t)h * NT + n] = tval[qf][r] * f;
          } else {
            int ml = n & 31, g = n >> 5;
            int hh = (ml >> 2) & 1, j = (ml & 3) + 4 * (ml >> 3);
            ktP[(size_t)h * NT + g * 32 + hh * 16 + j] = tval[qf][r];
          }
        }
    }
    __syncthreads();
    int row = t >> 1, half = t & 1;
    const short* src = lds_t + row * 136 + half * 64;
    short* dst = (z == 0 ? Qb : Kb) + ((size_t)h * NT + blockIdx.x * 128 + row) * DOUT + half * 64;
#pragma unroll
    for (int j = 0; j < 8; ++j)
      *(bf16x8*)(dst + j * 8) = *(const bf16x8*)(src + j * 8);
  } else {
    // V: stage transposed [d][n_local], stride 144
#pragma unroll
    for (int qf = 0; qf < 2; ++qf)
#pragma unroll
      for (int cf = 0; cf < 8; ++cf)
#pragma unroll
        for (int r = 0; r < 4; ++r)
          lds_t[(lr + 16 * cf) * 144 + w * 32 + 16 * qf + lg * 4 + r] = f2bf(acc[qf][cf][r]);
    if (lr == 0) {
#pragma unroll
      for (int qf = 0; qf < 2; ++qf)
#pragma unroll
        for (int r = 0; r < 4; ++r) {
          int n = n0w + 16 * qf + lg * 4 + r;
          int ml = n & 31, g = n >> 5;
          int hh = (ml >> 2) & 1, j = (ml & 3) + 4 * (ml >> 3);
          vtP[(size_t)h * NT + g * 32 + hh * 16 + j] = tval[qf][r];
        }
    }
    __syncthreads();
    int d = t >> 1, half = t & 1;
    const short* src = lds_t + d * 144 + half * 64;
    short* dst = VT + ((size_t)h * DOUT + d) * NT + blockIdx.x * 128 + half * 64;
#pragma unroll
    for (int j = 0; j < 8; ++j)
      *(bf16x8*)(dst + j * 8) = *(const bf16x8*)(src + j * 8);
  }
}

// ---------------- flash attention: swapped-operand 32x32x16, P in-register ----------------
// S^T = mfma(A=K, B=Q); max-free softmax (Lorentz logits <= 0); scale-invariant norms.
// P^T fragments via cvt_pk_bf16 + permlane32_swap; O^T = mfma(A=V^T, B=P^T).
// KV split NZ ways (compile-time). Partials linear -> plain coalesced stores (ATOMIC=0)
// into per-z buffers; ATOMIC=1 falls back to one memset'd buffer.
// XCD-AWARE 1-D GRID DECODE (T1): dispatch round-robins blockIdx across 8 XCDs, so with
//   xcd = bid&7, j = bid>>3, x = j&31, g = xcd + 8*(j>>5), h = g%NH, z = g/NH
// all 32 q-blocks sharing one (h,z) KV slice land on ONE XCD's L2. Round-7 lesson:
// nz=4 3-D grid spread sharers across XCDs -> FETCH 924MB (zero L2 absorption),
// latency-bound at MfmaUtil 9.6%. Requires grid % 8 == 0 and 12*NZ % 8 == 0.
// __launch_bounds__(256,3): live state ~150 unified regs (accO 64 f32 + bq + pk).
// Round-6's (256,5) forced spill -> 4.8GB scratch traffic. DO NOT raise.

template <int NZ, int ATOMIC>
__launch_bounds__(256, 3)
__global__ void k_attn(const short* __restrict__ Qb, const short* __restrict__ Kb,
                       const short* __restrict__ VT,
                       const float* __restrict__ qt, const float* __restrict__ ktP,
                       const float* __restrict__ vtP,
                       float* __restrict__ partz, float* __restrict__ avtz) {
  __shared__ __align__(16) char lds_all[32768];
  char* lds_k = lds_all;            // 16KB: [m][slot16] swizzled: slot ^= (m&15)
  char* lds_v = lds_all + 16384;    // 16KB: [d][slot16] swizzled: slot ^= (d&7)

  int t = threadIdx.x, l = t & 63, w = t >> 6;
  int ql = l & 31, hi = l >> 5;

  // XCD-aware decode (see header comment)
  int bid = blockIdx.x;
  int xcd = bid & 7, j = bid >> 3;
  int x = j & 31;
  int g = xcd + 8 * (j >> 5);       // 0 .. 12*NZ-1
  int h = g % NH, z = g / NH;

  constexpr int KPERZ = NT / (NZ * 64);
  int n0w = x * 128 + w * 32;
  int n = n0w + ql;

  const short* Qh = Qb + (size_t)h * NT * DOUT;
  const short* Kh = Kb + (size_t)h * NT * DOUT;
  const short* VTh = VT + (size_t)h * DOUT * NT;
  const float* ktPh = ktP + (size_t)h * NT;
  const float* vtPh = vtP + (size_t)h * NT;

  // Q as B-fragments: col=q=lane&31, k = dk*16 + hi*8 + e  (pre-scaled by c2)
  bf16x8 bq[8];
#pragma unroll
  for (int dk = 0; dk < 8; ++dk)
    bq[dk] = *(const bf16x8*)(Qh + (size_t)n * DOUT + dk * 16 + hi * 8);
  float qc2 = qt[(size_t)h * NT + n];

  f32x16 accO[4] = {};
  float avt = 0.f;

  int mz = z * (NT / NZ);

  // prologue: issue K tile 0 (source pre-swizzled, LDS linear)
#pragma unroll
  for (int it = 0; it < 4; ++it) {
    int c = t + it * 256;
    int m = c >> 4, s = c & 15;
    GL2LDS(Kh + (size_t)(mz + m) * DOUT + ((s ^ (m & 15)) * 8), lds_k + c * 16);
  }

  for (int ktile = 0; ktile < KPERZ; ++ktile) {
    int m0 = mz + ktile * 64;
    __syncthreads();   // K_t resident; lds_v free (prev PV done)

    // issue V_t (consumed after mid-barrier; latency hidden under QK^T+softmax)
#pragma unroll
    for (int it = 0; it < 4; ++it) {
      int c = t + it * 256;
      int d = c >> 3, s = c & 7;
      GL2LDS(VTh + (size_t)d * NT + m0 + ((s ^ (d & 7)) * 8), lds_v + c * 16);
    }

    bf16x8 pfrag[4];
#pragma unroll
    for (int mf = 0; mf < 2; ++mf) {
      // ---- QK^T (spatial): S^T tile, rows m = mf*32 + ql ----
      f32x16 accS = {};
      int m = mf * 32 + ql;
      int rowb = m * 256;
      int sx = m & 15;
      __builtin_amdgcn_s_setprio(1);
#pragma unroll
      for (int dk = 0; dk < 8; ++dk) {
        bf16x8 ak = *(const bf16x8*)(lds_k + rowb + (((dk * 2 + hi) ^ sx) * 16));
        accS = MFMA32(ak, bq[dk], accS);
      }
      __builtin_amdgcn_s_setprio(0);

      // ---- softmax + pack (max-free): p[j] = exp2(accS[j] - qc2*ktP[j]) ----
      const float* ktm = ktPh + m0 + mf * 32 + hi * 16;
      const float* vtm = vtPh + m0 + mf * 32 + hi * 16;
      unsigned pk[8];
#pragma unroll
      for (int i4 = 0; i4 < 4; ++i4) {
        f32x4 kt4 = *(const f32x4*)(ktm + i4 * 4);
        f32x4 vt4 = *(const f32x4*)(vtm + i4 * 4);
#pragma unroll
        for (int ii = 0; ii < 2; ++ii) {
          float a0 = fmaf(-qc2, kt4[2 * ii],     accS[i4 * 4 + 2 * ii]);
          float a1 = fmaf(-qc2, kt4[2 * ii + 1], accS[i4 * 4 + 2 * ii + 1]);
          float p0, p1;
          asm("v_exp_f32 %0, %1" : "=v"(p0) : "v"(a0));
          asm("v_exp_f32 %0, %1" : "=v"(p1) : "v"(a1));
          avt = fmaf(p0, vt4[2 * ii], avt);
          avt = fmaf(p1, vt4[2 * ii + 1], avt);
          unsigned pw;
          asm("v_cvt_pk_bf16_f32 %0, %1, %2" : "=v"(pw) : "v"(p0), "v"(p1));
          pk[i4 * 2 + ii] = pw;
        }
      }
      // redistribute: frag(ks) word pattern via permlane32_swap (pairs pk_i <-> pk_{i+2})
      asm volatile("v_permlane32_swap_b32 %0, %1" : "+v"(pk[0]), "+v"(pk[2]));
      asm volatile("v_permlane32_swap_b32 %0, %1" : "+v"(pk[1]), "+v"(pk[3]));
      asm volatile("v_permlane32_swap_b32 %0, %1" : "+v"(pk[4]), "+v"(pk[6]));
      asm volatile("v_permlane32_swap_b32 %0, %1" : "+v"(pk[5]), "+v"(pk[7]));
      union { unsigned u[4]; bf16x8 v; } f0, f1;
      f0.u[0] = pk[0]; f0.u[1] = pk[1]; f0.u[2] = pk[2]; f0.u[3] = pk[3];
      f1.u[0] = pk[4]; f1.u[1] = pk[5]; f1.u[2] = pk[6]; f1.u[3] = pk[7];
      pfrag[2 * mf] = f0.v;
      pfrag[2 * mf + 1] = f1.v;
    }

    __syncthreads();   // V_t resident; lds_k consumed by all waves

    // issue K_{t+1} (latency hidden under PV)
    if (ktile + 1 < KPERZ) {
      int m1 = m0 + 64;
#pragma unroll
      for (int it = 0; it < 4; ++it) {
        int c = t + it * 256;
        int m = c >> 4, s = c & 15;
        GL2LDS(Kh + (size_t)(m1 + m) * DOUT + ((s ^ (m & 15)) * 8), lds_k + c * 16);
      }
    }

    // ---- PV: O^T += V^T(d x m) . P^T(m x q) ----
    __builtin_amdgcn_s_setprio(1);
#pragma unroll
    for (int ks = 0; ks < 4; ++ks) {
#pragma unroll
      for (int df = 0; df < 4; ++df) {
        int d = df * 32 + ql;
        bf16x8 av = *(const bf16x8*)(lds_v + d * 128 + (((ks * 2 + hi) ^ (d & 7)) * 16));
        accO[df] = MFMA32(av, pfrag[ks], accO[df]);
      }
    }
    __builtin_amdgcn_s_setprio(0);
  }

  // ---- epilogue: per-wave LDS transpose -> coalesced plain stores (or atomics) ----
  __syncthreads();   // all waves done with lds_k/lds_v
  float* sc = (float*)(lds_all + w * 8192);   // 32 q x 64 d floats, XOR-swizzled (dl^ql)
  int zb = ATOMIC ? 0 : z;
  float* wbase = partz + (((size_t)zb * NH + h) * NT + n0w) * 128;
#pragma unroll
  for (int dh = 0; dh < 2; ++dh) {
#pragma unroll
    for (int j2 = 0; j2 < 2; ++j2)
#pragma unroll
      for (int r = 0; r < 16; ++r) {
        int dl = j2 * 32 + (r & 3) + 8 * (r >> 2) + 4 * hi;
        sc[ql * 64 + (dl ^ ql)] = accO[2 * dh + j2][r];
      }
    __syncthreads();
#pragma unroll
    for (int nl = 0; nl < 32; ++nl) {
      float v = sc[nl * 64 + (l ^ nl)];
      if (ATOMIC) atomicAdd(wbase + (size_t)nl * 128 + dh * 64 + l, v);
      else        wbase[(size_t)nl * 128 + dh * 64 + l] = v;
    }
    __syncthreads();
  }
  float avt2 = avt + __shfl_xor(avt, 32);
  if (l < 32) {
    float* ap = avtz + ((size_t)zb * NH + h) * NT + n0w + ql;
    if (ATOMIC) atomicAdd(ap, avt2);
    else        *ap = avt2;
  }
}

// ---------------- combine: midpoint-norm #1 per head, head sum, midpoint-norm #2 ----------------
// Sums nbuf z-partials; midpoint_norm scale-invariance -> no softmax denom, no 1/NH.

__global__ void k_comb(const float* __restrict__ partz, const float* __restrict__ avtz,
                       float* __restrict__ out, int nbuf) {
  int l = threadIdx.x & 63, w = threadIdx.x >> 6;
  int n = blockIdx.x * 4 + w;
  float acc_lo = 0.f, acc_hi = 0.f, acc_t = 0.f;
#pragma unroll
  for (int h = 0; h < NH; ++h) {
    float x = 0.f, y = 0.f, at = 0.f;
    for (int zb = 0; zb < nbuf; ++zb) {
      const float* p = partz + (((size_t)zb * NH + h) * NT + n) * 128;
      x += p[l]; y += p[64 + l];
      at += avtz[((size_t)zb * NH + h) * NT + n];
    }
    float sp = x * x + y * y;
    sp += __shfl_xor(sp, 1);  sp += __shfl_xor(sp, 2);
    sp += __shfl_xor(sp, 4);  sp += __shfl_xor(sp, 8);
    sp += __shfl_xor(sp, 16); sp += __shfl_xor(sp, 32);
    float inner = sp - at * at;
    float rd = 1.0f / sqrtf(fmaxf(fabsf(inner), 1e-8f));
    acc_lo += x * rd; acc_hi += y * rd; acc_t += at * rd;
  }
  float sp = acc_lo * acc_lo + acc_hi * acc_hi;
  sp += __shfl_xor(sp, 1);  sp += __shfl_xor(sp, 2);
  sp += __shfl_xor(sp, 4);  sp += __shfl_xor(sp, 8);
  sp += __shfl_xor(sp, 16); sp += __shfl_xor(sp, 32);
  float inner = sp - acc_t * acc_t;
  float rd = 1.0f / sqrtf(fmaxf(fabsf(inner), 1e-8f));
  float* orow = out + (size_t)n * D1;
  orow[1 + l] = acc_lo * rd;
  orow[65 + l] = acc_hi * rd;
  if (l == 0) orow[0] = acc_t * rd;
}

// ---------------- launch ----------------

extern "C" void kernel_launch(void* const* d_in, const int* in_sizes, int n_in,
                              void* d_out, int out_size, void* d_ws, size_t ws_size,
                              hipStream_t stream) {
  (void)in_sizes; (void)n_in; (void)out_size;
  const float* xl    = (const float*)d_in[0];
  const float* Wq    = (const float*)d_in[1];
  const float* bq    = (const float*)d_in[2];
  const float* Wk    = (const float*)d_in[3];
  const float* bk    = (const float*)d_in[4];
  const float* Wv    = (const float*)d_in[5];
  const float* bv    = (const float*)d_in[6];
  const float* scale = (const float*)d_in[7];
  // d_in[8] = bias: softmax shift-invariance + midpoint_norm scale-invariance -> no-op.
  float* out = (float*)d_out;

  char* ws = (char*)d_ws;
  size_t off = 0;
  auto alloc = [&](size_t b) { char* p = ws + off; off = (off + b + 255) & ~(size_t)255; return p; };
  auto al = [](size_t b) { return (b + 255) & ~(size_t)255; };

  // persistent buffers (live proj -> attn)
  short* Qb    = (short*)alloc((size_t)NH * NT * DOUT * 2);
  short* Kb    = (short*)alloc((size_t)NH * NT * DOUT * 2);
  short* VT    = (short*)alloc((size_t)NH * DOUT * NT * 2);
  float* qt    = (float*)alloc((size_t)NH * NT * 4);
  float* ktP   = (float*)alloc((size_t)NH * NT * 4);
  float* vtP   = (float*)alloc((size_t)NH * NT * 4);
  size_t base = off;

  // shared region: proj temporaries (xs, Wb) then reused for attention partials
  size_t xs_b = al((size_t)NT * INS * 2);
  size_t wb_b = al((size_t)3 * NH * DOUT * INS * 2);
  size_t projtmp = xs_b + wb_b;
  auto part_b = [&](int nb) {
    return al((size_t)nb * NH * NT * 128 * 4) + al((size_t)nb * NH * NT * 4);
  };

  // NZ = 2: all 768 blocks co-resident (3/CU), lockstep KV streaming.
  // mode ladder on workspace size: plain per-z buffers if they fit, else atomic.
  int nbuf, atomic;
  if (ws_size >= base + (projtmp > part_b(2) ? projtmp : part_b(2))) {
    nbuf = 2; atomic = 0;
  } else {
    nbuf = 1; atomic = 1;
  }

  char* region = ws + base;
  short* xs    = (short*)region;
  short* Wb    = (short*)(region + xs_b);
  float* partz = (float*)region;                                    // aliases xs/Wb (dead by then)
  float* avtz  = (float*)(region + al((size_t)nbuf * NH * NT * 128 * 4));

  if (atomic)
    hipMemsetAsync(partz, 0, part_b(1), stream);

  k_cvt_xs<<<NT, 256, 0, stream>>>(xl, xs);
  k_cvt_w<<<dim3(NH * DOUT * INS / 256, 3), 256, 0, stream>>>(Wq, Wk, Wv, Wb);
  k_proj<<<dim3(NT / 128, NH, 3), 256, 0, stream>>>(xs, Wb, bq, bk, bv, scale, Qb, Kb, VT, qt, ktP, vtP);
  if (atomic)
    k_attn<2, 1><<<(NT / 128) * NH * 2, 256, 0, stream>>>(Qb, Kb, VT, qt, ktP, vtP, partz, avtz);
  else
    k_attn<2, 0><<<(NT / 128) * NH * 2, 256, 0, stream>>>(Qb, Kb, VT, qt, ktP, vtP, partz, avtz);
  k_comb<<<NT / 4, 256, 0, stream>>>(partz, avtz, out, nbuf);
}